// Round 5
// baseline (345.175 us; speedup 1.0000x reference)
//
#include <hip/hip_runtime.h>
#include <hip/hip_fp16.h>
#include <math.h>

#define D 128

typedef __attribute__((ext_vector_type(8))) _Float16 half8;
typedef __attribute__((ext_vector_type(4))) float f32x4;

// Activations ys/hs live in SLICE-MAJOR layout: [8 slices][M rows][16 halves].
// Slice s = blockIdx.x % 8 in the agg kernels -> round-robin XCD mapping pins
// each 1.6 MB slice region into one XCD's 4 MiB L2: random gathers become L2 hits.

// ---------------- prep: WhT[l][n][k] = (half)Wl[k][n]  +  cnt zeroing ----------------

__global__ void prep_kernel(const float* __restrict__ W1, const float* __restrict__ W2,
                            const float* __restrict__ W3, __half* __restrict__ WhT,
                            int* __restrict__ cnt, int N) {
    int i = blockIdx.x * blockDim.x + threadIdx.x;
    if (i < 3 * D * D) {
        int l = i >> 14;
        int j = i & 16383;
        int n = j >> 7, k = j & 127;
        const float* W = (l == 0) ? W1 : (l == 1) ? W2 : W3;
        WhT[(size_t)i] = __float2half(W[(size_t)k * D + n]);
    }
    if (i < N) cnt[i] = 0;
}

// ---------------- graph build ----------------

// rank[e] = arrival order of edge e within its dst bucket; cnt[d] = in-degree
__global__ void count_rank_kernel(const int* __restrict__ dst, int* __restrict__ cnt,
                                  int* __restrict__ rank, int E) {
    int e0 = (blockIdx.x * blockDim.x + threadIdx.x) * 8;
    if (e0 + 7 < E) {
        int4 da = *(const int4*)(dst + e0);
        int4 db = *(const int4*)(dst + e0 + 4);
        int4 ra, rb;
        ra.x = atomicAdd(&cnt[da.x], 1);
        ra.y = atomicAdd(&cnt[da.y], 1);
        ra.z = atomicAdd(&cnt[da.z], 1);
        ra.w = atomicAdd(&cnt[da.w], 1);
        rb.x = atomicAdd(&cnt[db.x], 1);
        rb.y = atomicAdd(&cnt[db.y], 1);
        rb.z = atomicAdd(&cnt[db.z], 1);
        rb.w = atomicAdd(&cnt[db.w], 1);
        *(int4*)(rank + e0)     = ra;
        *(int4*)(rank + e0 + 4) = rb;
    } else {
        for (int e = e0; e < E; ++e) rank[e] = atomicAdd(&cnt[dst[e]], 1);
    }
}

// single-block scan, one barrier pass: per-thread contiguous chunk, two vector sweeps.
// cnt[N] -> rowptr[N+1]; dinv[i] = rsqrt(cnt[i]+1)
__global__ __launch_bounds__(1024) void scan_kernel(const int* __restrict__ cnt,
                                                    int* __restrict__ rowptr,
                                                    float* __restrict__ dinv,
                                                    int N) {
    __shared__ int wsum[16];
    int tid  = threadIdx.x;
    int lane = tid & 63;
    int wid  = tid >> 6;
    int C = ((N + 4095) / 4096) * 4;          // per-thread chunk, multiple of 4
    int start = tid * C;
    int end   = start + C; if (end > N) end = N;

    int local = 0;
    int i = start;
    for (; i + 3 < end; i += 4) {
        int4 v = *(const int4*)(cnt + i);
        local += v.x + v.y + v.z + v.w;
    }
    for (; i < end; ++i) local += cnt[i];

    int sc = local;
    #pragma unroll
    for (int off = 1; off < 64; off <<= 1) {
        int t = __shfl_up(sc, off, 64);
        if (lane >= off) sc += t;
    }
    if (lane == 63) wsum[wid] = sc;
    __syncthreads();
    if (tid < 16) {
        int w = wsum[tid];
        #pragma unroll
        for (int off = 1; off < 16; off <<= 1) {
            int t = __shfl_up(w, off, 16);
            if (tid >= off) w += t;
        }
        wsum[tid] = w;
    }
    __syncthreads();
    int run = ((wid > 0) ? wsum[wid - 1] : 0) + (sc - local);

    i = start;
    for (; i + 3 < end; i += 4) {
        int4 v = *(const int4*)(cnt + i);
        int4 rp;
        rp.x = run;
        rp.y = rp.x + v.x;
        rp.z = rp.y + v.y;
        rp.w = rp.z + v.z;
        run  = rp.w + v.w;
        *(int4*)(rowptr + i) = rp;
        float4 dv;
        dv.x = rsqrtf((float)v.x + 1.0f);
        dv.y = rsqrtf((float)v.y + 1.0f);
        dv.z = rsqrtf((float)v.z + 1.0f);
        dv.w = rsqrtf((float)v.w + 1.0f);
        *(float4*)(dinv + i) = dv;
    }
    for (; i < end; ++i) {
        int v = cnt[i];
        rowptr[i] = run; run += v;
        dinv[i] = rsqrtf((float)v + 1.0f);
    }
    if (tid == 0) rowptr[N] = wsum[15];
}

// ---------------- fill + gemm1 (fused by block range) ----------------
// fill: col[rowptr[dst[e]] + rank[e]] = src[e]   (rank-based, no atomics)
// gemm1: ys = dinv*(X @ W1), written SLICE-MAJOR.

__global__ __launch_bounds__(256) void fill_gemm1_kernel(
    const int* __restrict__ src, const int* __restrict__ dst,
    const int* __restrict__ rank, const int* __restrict__ rowptr,
    int* __restrict__ col, int E, int fill_blocks,
    const float* __restrict__ X, const __half* __restrict__ WhT,
    const float* __restrict__ dinv, __half* __restrict__ Y, int M) {
    int tid = threadIdx.x;
    if ((int)blockIdx.x < fill_blocks) {
        int e0 = (blockIdx.x * 256 + tid) * 8;
        if (e0 + 7 < E) {
            int4 da = *(const int4*)(dst + e0);
            int4 db = *(const int4*)(dst + e0 + 4);
            int4 ra = *(const int4*)(rank + e0);
            int4 rb = *(const int4*)(rank + e0 + 4);
            int4 sa = *(const int4*)(src + e0);
            int4 sb = *(const int4*)(src + e0 + 4);
            int p0 = rowptr[da.x] + ra.x;
            int p1 = rowptr[da.y] + ra.y;
            int p2 = rowptr[da.z] + ra.z;
            int p3 = rowptr[da.w] + ra.w;
            int p4 = rowptr[db.x] + rb.x;
            int p5 = rowptr[db.y] + rb.y;
            int p6 = rowptr[db.z] + rb.z;
            int p7 = rowptr[db.w] + rb.w;
            col[p0] = sa.x; col[p1] = sa.y; col[p2] = sa.z; col[p3] = sa.w;
            col[p4] = sb.x; col[p5] = sb.y; col[p6] = sb.z; col[p7] = sb.w;
        } else {
            for (int e = e0; e < E; ++e) col[rowptr[dst[e]] + rank[e]] = src[e];
        }
        return;
    }
    int bid  = blockIdx.x - fill_blocks;
    int wave = tid >> 6;
    int lane = tid & 63;
    int quad = lane >> 4;
    int l16  = lane & 15;
    int m0   = bid * 64 + wave * 16;
    if (m0 >= M) return;

    f32x4 acc[8];
    #pragma unroll
    for (int t = 0; t < 8; ++t) acc[t] = (f32x4)0.0f;

    const float* xrow = X + (size_t)(m0 + l16) * D;

    #pragma unroll
    for (int ks = 0; ks < 4; ++ks) {
        int k0 = ks * 32 + quad * 8;
        float4 x0 = *(const float4*)(xrow + k0);
        float4 x1 = *(const float4*)(xrow + k0 + 4);
        half8 a;
        a[0] = (_Float16)x0.x; a[1] = (_Float16)x0.y;
        a[2] = (_Float16)x0.z; a[3] = (_Float16)x0.w;
        a[4] = (_Float16)x1.x; a[5] = (_Float16)x1.y;
        a[6] = (_Float16)x1.z; a[7] = (_Float16)x1.w;
        #pragma unroll
        for (int t = 0; t < 8; ++t) {
            half8 b = *(const half8*)(WhT + (size_t)(t * 16 + l16) * D + k0);
            acc[t] = __builtin_amdgcn_mfma_f32_16x16x32_f16(a, b, acc[t], 0, 0, 0);
        }
    }

    float4 dv = *(const float4*)(dinv + m0 + quad * 4);
    float dvs[4] = {dv.x, dv.y, dv.z, dv.w};
    #pragma unroll
    for (int t = 0; t < 8; ++t) {       // t == slice
        #pragma unroll
        for (int r = 0; r < 4; ++r) {
            int grow = m0 + quad * 4 + r;
            Y[((size_t)t * M + grow) * 16 + l16] = __float2half(acc[t][r] * dvs[r]);
        }
    }
}

// ---------------- standalone GEMM, slice-major in/out: Y = dinv*(Xs @ W) ----------------

__global__ __launch_bounds__(256) void gemm_s_kernel(const __half* __restrict__ Xs,
                                                     const __half* __restrict__ WhT,
                                                     const float* __restrict__ dinv,
                                                     __half* __restrict__ Ys, int M) {
    int tid  = threadIdx.x;
    int wave = tid >> 6;
    int lane = tid & 63;
    int quad = lane >> 4;
    int l16  = lane & 15;
    int m0   = blockIdx.x * 64 + wave * 16;
    if (m0 >= M) return;

    f32x4 acc[8];
    #pragma unroll
    for (int t = 0; t < 8; ++t) acc[t] = (f32x4)0.0f;

    int arow = m0 + l16;

    #pragma unroll
    for (int ks = 0; ks < 4; ++ks) {
        int k0 = ks * 32 + quad * 8;
        // A[arow][k0..k0+8): slice-major: slice = k0>>4, offset = k0&15 (0 or 8)
        half8 a = *(const half8*)(Xs + ((size_t)(k0 >> 4) * M + arow) * 16 + (k0 & 15));
        #pragma unroll
        for (int t = 0; t < 8; ++t) {
            half8 b = *(const half8*)(WhT + (size_t)(t * 16 + l16) * D + k0);
            acc[t] = __builtin_amdgcn_mfma_f32_16x16x32_f16(a, b, acc[t], 0, 0, 0);
        }
    }

    float4 dv = *(const float4*)(dinv + m0 + quad * 4);
    float dvs[4] = {dv.x, dv.y, dv.z, dv.w};
    #pragma unroll
    for (int t = 0; t < 8; ++t) {       // t == slice
        #pragma unroll
        for (int r = 0; r < 4; ++r) {
            int grow = m0 + quad * 4 + r;
            Ys[((size_t)t * M + grow) * 16 + l16] = __float2half(acc[t][r] * dvs[r]);
        }
    }
}

// ---------------- XCD-sliced aggregation ----------------
// Block -> (chunk, slice): slice = bid % 8 rides the round-robin block->XCD map,
// so each XCD only ever gathers from its own 1.6 MB slice region (L2-resident).
// Wave: 8 groups x 8 lanes; group g owns one dst row, lane l8 owns 2 cols (4 B).
// 32 rows/block. FINAL: write fp32 row-major out (no relu); else half slice-major + relu.

template <bool FINAL>
__global__ __launch_bounds__(256) void agg_slice_kernel(
    const __half* __restrict__ ysIn, const int* __restrict__ rowptr,
    const int* __restrict__ col, const float* __restrict__ dinv,
    const float* __restrict__ bias, __half* __restrict__ outh,
    float* __restrict__ outf, int M) {
    int bid   = blockIdx.x;
    int slice = bid & 7;
    int chunk = bid >> 3;
    int tid  = threadIdx.x;
    int wave = tid >> 6;
    int lane = tid & 63;
    int g    = lane >> 3;
    int l8   = lane & 7;
    int row  = chunk * 32 + wave * 8 + g;
    bool valid = row < M;
    int c = valid ? row : M - 1;

    const __half* base = ysIn + (size_t)slice * M * 16;
    int s = rowptr[c], e = rowptr[c + 1];

    float2 bb = ((const float2*)bias)[slice * 8 + l8];

    __half2 hself = *(const __half2*)(base + (size_t)c * 16 + l8 * 2);
    float a0x = __low2float(hself), a0y = __high2float(hself);
    float a1x = 0.f, a1y = 0.f, a2x = 0.f, a2y = 0.f, a3x = 0.f, a3y = 0.f;

    int j = s;
    for (; j + 8 <= e; j += 8) {
        int c0 = col[j + 0], c1 = col[j + 1], c2 = col[j + 2], c3 = col[j + 3];
        int c4 = col[j + 4], c5 = col[j + 5], c6 = col[j + 6], c7 = col[j + 7];
        __half2 v0 = *(const __half2*)(base + (size_t)c0 * 16 + l8 * 2);
        __half2 v1 = *(const __half2*)(base + (size_t)c1 * 16 + l8 * 2);
        __half2 v2 = *(const __half2*)(base + (size_t)c2 * 16 + l8 * 2);
        __half2 v3 = *(const __half2*)(base + (size_t)c3 * 16 + l8 * 2);
        __half2 v4 = *(const __half2*)(base + (size_t)c4 * 16 + l8 * 2);
        __half2 v5 = *(const __half2*)(base + (size_t)c5 * 16 + l8 * 2);
        __half2 v6 = *(const __half2*)(base + (size_t)c6 * 16 + l8 * 2);
        __half2 v7 = *(const __half2*)(base + (size_t)c7 * 16 + l8 * 2);
        a0x += __low2float(v0); a0y += __high2float(v0);
        a1x += __low2float(v1); a1y += __high2float(v1);
        a2x += __low2float(v2); a2y += __high2float(v2);
        a3x += __low2float(v3); a3y += __high2float(v3);
        a0x += __low2float(v4); a0y += __high2float(v4);
        a1x += __low2float(v5); a1y += __high2float(v5);
        a2x += __low2float(v6); a2y += __high2float(v6);
        a3x += __low2float(v7); a3y += __high2float(v7);
    }
    for (; j + 4 <= e; j += 4) {
        int c0 = col[j + 0], c1 = col[j + 1], c2 = col[j + 2], c3 = col[j + 3];
        __half2 v0 = *(const __half2*)(base + (size_t)c0 * 16 + l8 * 2);
        __half2 v1 = *(const __half2*)(base + (size_t)c1 * 16 + l8 * 2);
        __half2 v2 = *(const __half2*)(base + (size_t)c2 * 16 + l8 * 2);
        __half2 v3 = *(const __half2*)(base + (size_t)c3 * 16 + l8 * 2);
        a0x += __low2float(v0); a0y += __high2float(v0);
        a1x += __low2float(v1); a1y += __high2float(v1);
        a2x += __low2float(v2); a2y += __high2float(v2);
        a3x += __low2float(v3); a3y += __high2float(v3);
    }
    for (; j < e; ++j) {
        int c0 = col[j];
        __half2 v0 = *(const __half2*)(base + (size_t)c0 * 16 + l8 * 2);
        a0x += __low2float(v0); a0y += __high2float(v0);
    }
    a0x += a1x + a2x + a3x;
    a0y += a1y + a2y + a3y;

    float dv = dinv[c];
    float rx = bb.x + dv * a0x;
    float ry = bb.y + dv * a0y;
    if (valid) {
        if (FINAL) {
            *(float2*)(outf + (size_t)row * D + slice * 16 + l8 * 2) = make_float2(rx, ry);
        } else {
            __half2 hv = __floats2half2_rn(fmaxf(rx, 0.f), fmaxf(ry, 0.f));
            *(__half2*)(outh + ((size_t)slice * M + row) * 16 + l8 * 2) = hv;
        }
    }
}

// ---------------- launch ----------------

extern "C" void kernel_launch(void* const* d_in, const int* in_sizes, int n_in,
                              void* d_out, int out_size, void* d_ws, size_t ws_size,
                              hipStream_t stream) {
    const float* x   = (const float*)d_in[0];
    const int*   ei  = (const int*)d_in[1];
    const float* W1  = (const float*)d_in[2];
    const float* b1  = (const float*)d_in[3];
    const float* W2  = (const float*)d_in[4];
    const float* b2  = (const float*)d_in[5];
    const float* W3  = (const float*)d_in[6];
    const float* b3  = (const float*)d_in[7];
    float* out = (float*)d_out;

    const int N = in_sizes[0] / D;
    const int E = in_sizes[1] / 2;
    const int* src = ei;
    const int* dst = ei + E;

    char* ws = (char*)d_ws;
    size_t off = 0;
    auto alloc = [&](size_t bytes) {
        void* p = ws + off;
        off = (off + bytes + 255) & ~(size_t)255;
        return p;
    };
    __half* ys    = (__half*)alloc((size_t)N * D * sizeof(__half));   // slice-major
    __half* hs    = (__half*)alloc((size_t)N * D * sizeof(__half));   // slice-major
    int*   cnt    = (int*)alloc((size_t)N * sizeof(int));
    int*   rowptr = (int*)alloc((size_t)(N + 1) * sizeof(int));
    float* dinv   = (float*)alloc((size_t)N * sizeof(float));
    int*   rank   = (int*)alloc((size_t)E * sizeof(int));
    int*   col    = (int*)alloc((size_t)E * sizeof(int));
    __half* WhT   = (__half*)alloc((size_t)3 * D * D * sizeof(__half));
    (void)ws_size; (void)n_in; (void)out_size;

    // 1. prep: W transpose/convert + cnt zero
    int prep_threads = (3 * D * D > N) ? 3 * D * D : N;
    prep_kernel<<<(prep_threads + 255) / 256, 256, 0, stream>>>(W1, W2, W3, WhT, cnt, N);

    // 2-3. count+rank, scan
    const int egrid = ((E + 7) / 8 + 255) / 256;
    count_rank_kernel<<<egrid, 256, 0, stream>>>(dst, cnt, rank, E);
    scan_kernel<<<1, 1024, 0, stream>>>(cnt, rowptr, dinv, N);

    // 4. fill + gemm1 fused (gemm1 writes slice-major ys)
    const int gemm_grid = (N + 63) / 64;
    fill_gemm1_kernel<<<egrid + gemm_grid, 256, 0, stream>>>(
        src, dst, rank, rowptr, col, E, egrid, x, WhT, dinv, ys, N);

    // 5-9. sliced agg / slice-major gemm alternation
    const int nchunk = (N + 31) / 32;
    const int agg_grid = nchunk * 8;
    agg_slice_kernel<false><<<agg_grid, 256, 0, stream>>>(ys, rowptr, col, dinv, b1, hs, nullptr, N);
    gemm_s_kernel<<<gemm_grid, 256, 0, stream>>>(hs, WhT + 16384, dinv, ys, N);
    agg_slice_kernel<false><<<agg_grid, 256, 0, stream>>>(ys, rowptr, col, dinv, b2, hs, nullptr, N);
    gemm_s_kernel<<<gemm_grid, 256, 0, stream>>>(hs, WhT + 32768, dinv, ys, N);
    agg_slice_kernel<true><<<agg_grid, 256, 0, stream>>>(ys, rowptr, col, dinv, b3, nullptr, out, N);
}

// Round 6
// 338.906 us; speedup vs baseline: 1.0185x; 1.0185x over previous
//
#include <hip/hip_runtime.h>
#include <hip/hip_fp16.h>
#include <math.h>

#define D 128

typedef __attribute__((ext_vector_type(8))) _Float16 half8;
typedef __attribute__((ext_vector_type(4))) float f32x4;

// Activations ys/hs live in SLICE-MAJOR layout: [4 slices][M rows][32 halves].
// Slice s = blockIdx.x & 3 with sub-half (blockIdx.x>>2)&1: XCD pair {s, s+4}
// (via the %8 round-robin block->XCD map, confirmed by R5's FETCH collapse)
// each pin the 3.2 MB slice into their 4 MiB L2 -> random gathers are L2 hits,
// at HALF of R5's request count (64 B per request instead of 32 B).

// ---------------- prep: WhT[l][n][k] = (half)Wl[k][n]  +  cnt zeroing ----------------

__global__ void prep_kernel(const float* __restrict__ W1, const float* __restrict__ W2,
                            const float* __restrict__ W3, __half* __restrict__ WhT,
                            int* __restrict__ cnt, int N) {
    int i = blockIdx.x * blockDim.x + threadIdx.x;
    if (i < 3 * D * D) {
        int l = i >> 14;
        int j = i & 16383;
        int n = j >> 7, k = j & 127;
        const float* W = (l == 0) ? W1 : (l == 1) ? W2 : W3;
        WhT[(size_t)i] = __float2half(W[(size_t)k * D + n]);
    }
    if (i < N) cnt[i] = 0;
}

// ---------------- graph build ----------------

// rank[e] = arrival order of edge e within its dst bucket; cnt[d] = in-degree
__global__ void count_rank_kernel(const int* __restrict__ dst, int* __restrict__ cnt,
                                  int* __restrict__ rank, int E) {
    int e0 = (blockIdx.x * blockDim.x + threadIdx.x) * 8;
    if (e0 + 7 < E) {
        int4 da = *(const int4*)(dst + e0);
        int4 db = *(const int4*)(dst + e0 + 4);
        int4 ra, rb;
        ra.x = atomicAdd(&cnt[da.x], 1);
        ra.y = atomicAdd(&cnt[da.y], 1);
        ra.z = atomicAdd(&cnt[da.z], 1);
        ra.w = atomicAdd(&cnt[da.w], 1);
        rb.x = atomicAdd(&cnt[db.x], 1);
        rb.y = atomicAdd(&cnt[db.y], 1);
        rb.z = atomicAdd(&cnt[db.z], 1);
        rb.w = atomicAdd(&cnt[db.w], 1);
        *(int4*)(rank + e0)     = ra;
        *(int4*)(rank + e0 + 4) = rb;
    } else {
        for (int e = e0; e < E; ++e) rank[e] = atomicAdd(&cnt[dst[e]], 1);
    }
}

// single-block scan, one barrier pass: per-thread contiguous chunk, two vector sweeps.
// cnt[N] -> rowptr[N+1]; dinv[i] = rsqrt(cnt[i]+1)
__global__ __launch_bounds__(1024) void scan_kernel(const int* __restrict__ cnt,
                                                    int* __restrict__ rowptr,
                                                    float* __restrict__ dinv,
                                                    int N) {
    __shared__ int wsum[16];
    int tid  = threadIdx.x;
    int lane = tid & 63;
    int wid  = tid >> 6;
    int C = ((N + 4095) / 4096) * 4;          // per-thread chunk, multiple of 4
    int start = tid * C;
    int end   = start + C; if (end > N) end = N;

    int local = 0;
    int i = start;
    for (; i + 3 < end; i += 4) {
        int4 v = *(const int4*)(cnt + i);
        local += v.x + v.y + v.z + v.w;
    }
    for (; i < end; ++i) local += cnt[i];

    int sc = local;
    #pragma unroll
    for (int off = 1; off < 64; off <<= 1) {
        int t = __shfl_up(sc, off, 64);
        if (lane >= off) sc += t;
    }
    if (lane == 63) wsum[wid] = sc;
    __syncthreads();
    if (tid < 16) {
        int w = wsum[tid];
        #pragma unroll
        for (int off = 1; off < 16; off <<= 1) {
            int t = __shfl_up(w, off, 16);
            if (tid >= off) w += t;
        }
        wsum[tid] = w;
    }
    __syncthreads();
    int run = ((wid > 0) ? wsum[wid - 1] : 0) + (sc - local);

    i = start;
    for (; i + 3 < end; i += 4) {
        int4 v = *(const int4*)(cnt + i);
        int4 rp;
        rp.x = run;
        rp.y = rp.x + v.x;
        rp.z = rp.y + v.y;
        rp.w = rp.z + v.z;
        run  = rp.w + v.w;
        *(int4*)(rowptr + i) = rp;
        float4 dv;
        dv.x = rsqrtf((float)v.x + 1.0f);
        dv.y = rsqrtf((float)v.y + 1.0f);
        dv.z = rsqrtf((float)v.z + 1.0f);
        dv.w = rsqrtf((float)v.w + 1.0f);
        *(float4*)(dinv + i) = dv;
    }
    for (; i < end; ++i) {
        int v = cnt[i];
        rowptr[i] = run; run += v;
        dinv[i] = rsqrtf((float)v + 1.0f);
    }
    if (tid == 0) rowptr[N] = wsum[15];
}

// ---------------- fill + gemm1 (fused by block range) ----------------
// fill: col[rowptr[dst[e]] + rank[e]] = src[e]   (rank-based, no atomics)
// gemm1: ys = dinv*(X @ W1), written SLICE-MAJOR [4][M][32].

__global__ __launch_bounds__(256) void fill_gemm1_kernel(
    const int* __restrict__ src, const int* __restrict__ dst,
    const int* __restrict__ rank, const int* __restrict__ rowptr,
    int* __restrict__ col, int E, int fill_blocks,
    const float* __restrict__ X, const __half* __restrict__ WhT,
    const float* __restrict__ dinv, __half* __restrict__ Y, int M) {
    int tid = threadIdx.x;
    if ((int)blockIdx.x < fill_blocks) {
        int e0 = (blockIdx.x * 256 + tid) * 8;
        if (e0 + 7 < E) {
            int4 da = *(const int4*)(dst + e0);
            int4 db = *(const int4*)(dst + e0 + 4);
            int4 ra = *(const int4*)(rank + e0);
            int4 rb = *(const int4*)(rank + e0 + 4);
            int4 sa = *(const int4*)(src + e0);
            int4 sb = *(const int4*)(src + e0 + 4);
            int p0 = rowptr[da.x] + ra.x;
            int p1 = rowptr[da.y] + ra.y;
            int p2 = rowptr[da.z] + ra.z;
            int p3 = rowptr[da.w] + ra.w;
            int p4 = rowptr[db.x] + rb.x;
            int p5 = rowptr[db.y] + rb.y;
            int p6 = rowptr[db.z] + rb.z;
            int p7 = rowptr[db.w] + rb.w;
            col[p0] = sa.x; col[p1] = sa.y; col[p2] = sa.z; col[p3] = sa.w;
            col[p4] = sb.x; col[p5] = sb.y; col[p6] = sb.z; col[p7] = sb.w;
        } else {
            for (int e = e0; e < E; ++e) col[rowptr[dst[e]] + rank[e]] = src[e];
        }
        return;
    }
    int bid  = blockIdx.x - fill_blocks;
    int wave = tid >> 6;
    int lane = tid & 63;
    int quad = lane >> 4;
    int l16  = lane & 15;
    int m0   = bid * 64 + wave * 16;
    if (m0 >= M) return;

    f32x4 acc[8];
    #pragma unroll
    for (int t = 0; t < 8; ++t) acc[t] = (f32x4)0.0f;

    const float* xrow = X + (size_t)(m0 + l16) * D;

    #pragma unroll
    for (int ks = 0; ks < 4; ++ks) {
        int k0 = ks * 32 + quad * 8;
        float4 x0 = *(const float4*)(xrow + k0);
        float4 x1 = *(const float4*)(xrow + k0 + 4);
        half8 a;
        a[0] = (_Float16)x0.x; a[1] = (_Float16)x0.y;
        a[2] = (_Float16)x0.z; a[3] = (_Float16)x0.w;
        a[4] = (_Float16)x1.x; a[5] = (_Float16)x1.y;
        a[6] = (_Float16)x1.z; a[7] = (_Float16)x1.w;
        #pragma unroll
        for (int t = 0; t < 8; ++t) {
            half8 b = *(const half8*)(WhT + (size_t)(t * 16 + l16) * D + k0);
            acc[t] = __builtin_amdgcn_mfma_f32_16x16x32_f16(a, b, acc[t], 0, 0, 0);
        }
    }

    float4 dv = *(const float4*)(dinv + m0 + quad * 4);
    float dvs[4] = {dv.x, dv.y, dv.z, dv.w};
    #pragma unroll
    for (int t = 0; t < 8; ++t) {       // output cols t*16+l16 -> slice t>>1
        #pragma unroll
        for (int r = 0; r < 4; ++r) {
            int grow = m0 + quad * 4 + r;
            Y[((size_t)(t >> 1) * M + grow) * 32 + (t & 1) * 16 + l16] =
                __float2half(acc[t][r] * dvs[r]);
        }
    }
}

// ---------------- standalone GEMM, slice-major [4][M][32] in/out ----------------

__global__ __launch_bounds__(256) void gemm_s_kernel(const __half* __restrict__ Xs,
                                                     const __half* __restrict__ WhT,
                                                     const float* __restrict__ dinv,
                                                     __half* __restrict__ Ys, int M) {
    int tid  = threadIdx.x;
    int wave = tid >> 6;
    int lane = tid & 63;
    int quad = lane >> 4;
    int l16  = lane & 15;
    int m0   = blockIdx.x * 64 + wave * 16;
    if (m0 >= M) return;

    f32x4 acc[8];
    #pragma unroll
    for (int t = 0; t < 8; ++t) acc[t] = (f32x4)0.0f;

    int arow = m0 + l16;

    #pragma unroll
    for (int ks = 0; ks < 4; ++ks) {
        int k0 = ks * 32 + quad * 8;
        // A[arow][k0..k0+8): slice = ks, offset quad*8 within the 32-col slice row
        half8 a = *(const half8*)(Xs + ((size_t)ks * M + arow) * 32 + quad * 8);
        #pragma unroll
        for (int t = 0; t < 8; ++t) {
            half8 b = *(const half8*)(WhT + (size_t)(t * 16 + l16) * D + k0);
            acc[t] = __builtin_amdgcn_mfma_f32_16x16x32_f16(a, b, acc[t], 0, 0, 0);
        }
    }

    float4 dv = *(const float4*)(dinv + m0 + quad * 4);
    float dvs[4] = {dv.x, dv.y, dv.z, dv.w};
    #pragma unroll
    for (int t = 0; t < 8; ++t) {
        #pragma unroll
        for (int r = 0; r < 4; ++r) {
            int grow = m0 + quad * 4 + r;
            Ys[((size_t)(t >> 1) * M + grow) * 32 + (t & 1) * 16 + l16] =
                __float2half(acc[t][r] * dvs[r]);
        }
    }
}

// ---------------- XCD-sliced aggregation (4 x 32-col slices) ----------------
// Block -> (chunk, sub, slice): slice = bid&3, sub = (bid>>2)&1, chunk = bid>>3.
// Wave: 4 groups x 16 lanes; group owns one dst row, lane l16 owns 2 cols (4 B);
// one gather instruction = 4 rows x 64 B (full row-slice) -> half R5's requests.
// 32 rows/block (2 steps x 4 waves x 4 groups).

template <bool FINAL>
__global__ __launch_bounds__(256) void agg_slice4_kernel(
    const __half* __restrict__ ysIn, const int* __restrict__ rowptr,
    const int* __restrict__ col, const float* __restrict__ dinv,
    const float* __restrict__ bias, __half* __restrict__ outh,
    float* __restrict__ outf, int M) {
    int bid   = blockIdx.x;
    int slice = bid & 3;
    int sub   = (bid >> 2) & 1;
    int chunk = bid >> 3;
    int row0  = (chunk * 2 + sub) * 32;
    int tid  = threadIdx.x;
    int wave = tid >> 6;
    int lane = tid & 63;
    int g    = lane >> 4;
    int l16  = lane & 15;

    const __half* base = ysIn + (size_t)slice * M * 32;
    float2 bb = ((const float2*)bias)[slice * 16 + l16];

    #pragma unroll
    for (int t = 0; t < 2; ++t) {
        int row = row0 + t * 16 + wave * 4 + g;
        bool valid = row < M;
        int c = valid ? row : M - 1;
        int s = rowptr[c], e = rowptr[c + 1];

        __half2 hself = *(const __half2*)(base + (size_t)c * 32 + l16 * 2);
        float a0x = __low2float(hself), a0y = __high2float(hself);
        float a1x = 0.f, a1y = 0.f, a2x = 0.f, a2y = 0.f, a3x = 0.f, a3y = 0.f;

        int j = s;
        for (; j + 8 <= e; j += 8) {
            int c0 = col[j + 0], c1 = col[j + 1], c2 = col[j + 2], c3 = col[j + 3];
            int c4 = col[j + 4], c5 = col[j + 5], c6 = col[j + 6], c7 = col[j + 7];
            __half2 v0 = *(const __half2*)(base + (size_t)c0 * 32 + l16 * 2);
            __half2 v1 = *(const __half2*)(base + (size_t)c1 * 32 + l16 * 2);
            __half2 v2 = *(const __half2*)(base + (size_t)c2 * 32 + l16 * 2);
            __half2 v3 = *(const __half2*)(base + (size_t)c3 * 32 + l16 * 2);
            __half2 v4 = *(const __half2*)(base + (size_t)c4 * 32 + l16 * 2);
            __half2 v5 = *(const __half2*)(base + (size_t)c5 * 32 + l16 * 2);
            __half2 v6 = *(const __half2*)(base + (size_t)c6 * 32 + l16 * 2);
            __half2 v7 = *(const __half2*)(base + (size_t)c7 * 32 + l16 * 2);
            a0x += __low2float(v0); a0y += __high2float(v0);
            a1x += __low2float(v1); a1y += __high2float(v1);
            a2x += __low2float(v2); a2y += __high2float(v2);
            a3x += __low2float(v3); a3y += __high2float(v3);
            a0x += __low2float(v4); a0y += __high2float(v4);
            a1x += __low2float(v5); a1y += __high2float(v5);
            a2x += __low2float(v6); a2y += __high2float(v6);
            a3x += __low2float(v7); a3y += __high2float(v7);
        }
        for (; j + 4 <= e; j += 4) {
            int c0 = col[j + 0], c1 = col[j + 1], c2 = col[j + 2], c3 = col[j + 3];
            __half2 v0 = *(const __half2*)(base + (size_t)c0 * 32 + l16 * 2);
            __half2 v1 = *(const __half2*)(base + (size_t)c1 * 32 + l16 * 2);
            __half2 v2 = *(const __half2*)(base + (size_t)c2 * 32 + l16 * 2);
            __half2 v3 = *(const __half2*)(base + (size_t)c3 * 32 + l16 * 2);
            a0x += __low2float(v0); a0y += __high2float(v0);
            a1x += __low2float(v1); a1y += __high2float(v1);
            a2x += __low2float(v2); a2y += __high2float(v2);
            a3x += __low2float(v3); a3y += __high2float(v3);
        }
        for (; j < e; ++j) {
            int c0 = col[j];
            __half2 v0 = *(const __half2*)(base + (size_t)c0 * 32 + l16 * 2);
            a0x += __low2float(v0); a0y += __high2float(v0);
        }
        a0x += a1x + a2x + a3x;
        a0y += a1y + a2y + a3y;

        float dv = dinv[c];
        float rx = bb.x + dv * a0x;
        float ry = bb.y + dv * a0y;
        if (valid) {
            if (FINAL) {
                *(float2*)(outf + (size_t)row * D + slice * 32 + l16 * 2) = make_float2(rx, ry);
            } else {
                __half2 hv = __floats2half2_rn(fmaxf(rx, 0.f), fmaxf(ry, 0.f));
                *(__half2*)(outh + ((size_t)slice * M + row) * 32 + l16 * 2) = hv;
            }
        }
    }
}

// ---------------- launch ----------------

extern "C" void kernel_launch(void* const* d_in, const int* in_sizes, int n_in,
                              void* d_out, int out_size, void* d_ws, size_t ws_size,
                              hipStream_t stream) {
    const float* x   = (const float*)d_in[0];
    const int*   ei  = (const int*)d_in[1];
    const float* W1  = (const float*)d_in[2];
    const float* b1  = (const float*)d_in[3];
    const float* W2  = (const float*)d_in[4];
    const float* b2  = (const float*)d_in[5];
    const float* W3  = (const float*)d_in[6];
    const float* b3  = (const float*)d_in[7];
    float* out = (float*)d_out;

    const int N = in_sizes[0] / D;
    const int E = in_sizes[1] / 2;
    const int* src = ei;
    const int* dst = ei + E;

    char* ws = (char*)d_ws;
    size_t off = 0;
    auto alloc = [&](size_t bytes) {
        void* p = ws + off;
        off = (off + bytes + 255) & ~(size_t)255;
        return p;
    };
    __half* ys    = (__half*)alloc((size_t)N * D * sizeof(__half));   // slice-major [4][N][32]
    __half* hs    = (__half*)alloc((size_t)N * D * sizeof(__half));   // slice-major [4][N][32]
    int*   cnt    = (int*)alloc((size_t)N * sizeof(int));
    int*   rowptr = (int*)alloc((size_t)(N + 1) * sizeof(int));
    float* dinv   = (float*)alloc((size_t)N * sizeof(float));
    int*   rank   = (int*)alloc((size_t)E * sizeof(int));
    int*   col    = (int*)alloc((size_t)E * sizeof(int));
    __half* WhT   = (__half*)alloc((size_t)3 * D * D * sizeof(__half));
    (void)ws_size; (void)n_in; (void)out_size;

    // 1. prep: W transpose/convert + cnt zero
    int prep_threads = (3 * D * D > N) ? 3 * D * D : N;
    prep_kernel<<<(prep_threads + 255) / 256, 256, 0, stream>>>(W1, W2, W3, WhT, cnt, N);

    // 2-3. count+rank, scan
    const int egrid = ((E + 7) / 8 + 255) / 256;
    count_rank_kernel<<<egrid, 256, 0, stream>>>(dst, cnt, rank, E);
    scan_kernel<<<1, 1024, 0, stream>>>(cnt, rowptr, dinv, N);

    // 4. fill + gemm1 fused (gemm1 writes slice-major ys)
    const int gemm_grid = (N + 63) / 64;
    fill_gemm1_kernel<<<egrid + gemm_grid, 256, 0, stream>>>(
        src, dst, rank, rowptr, col, E, egrid, x, WhT, dinv, ys, N);

    // 5-9. sliced agg / slice-major gemm alternation
    const int rows32 = (N + 31) / 32;
    const int nchunk = (rows32 + 1) / 2;
    const int agg_grid = nchunk * 8;
    agg_slice4_kernel<false><<<agg_grid, 256, 0, stream>>>(ys, rowptr, col, dinv, b1, hs, nullptr, N);
    gemm_s_kernel<<<gemm_grid, 256, 0, stream>>>(hs, WhT + 16384, dinv, ys, N);
    agg_slice4_kernel<false><<<agg_grid, 256, 0, stream>>>(ys, rowptr, col, dinv, b2, hs, nullptr, N);
    gemm_s_kernel<<<gemm_grid, 256, 0, stream>>>(hs, WhT + 32768, dinv, ys, N);
    agg_slice4_kernel<true><<<agg_grid, 256, 0, stream>>>(ys, rowptr, col, dinv, b3, nullptr, out, N);
}